// Round 3
// baseline (297.636 us; speedup 1.0000x reference)
//
#include <hip/hip_runtime.h>

#define B_   32
#define L_   256
#define T_   4096
#define YMAX 129            // y_max = W+1
#define NW   128            // n_words
#define NROW (B_ * YMAX)    // 4128

// sub4(v) = ((v-1)//2 - 1)//2 with Python floor semantics
__device__ __forceinline__ int sub4i(int v) {
    return (((v - 1) >> 1) - 1) >> 1;
}

// ---------------------------------------------------------------------------
// Single fused kernel. One block per (b, y):
//  1. recompute row metadata from wbeg/wend (ballot/popcount compaction; the
//     2 KB index rows are shared by all 129 blocks of a batch -> L2 hits)
//  2. y==0 blocks build tgt0 in LDS via diff-array + block scan
//  3. BCE over the row's <=2 token rows (float4, each tse element read once)
//  4. per-block partial -> ws; last-arriving block (agent-scope counter)
//     reduces all partials and writes the scalar output
// ---------------------------------------------------------------------------
__global__ __launch_bounds__(256) void fused_kernel(
    const float* __restrict__ tse, const int* __restrict__ wbeg,
    const int* __restrict__ wend, const int* __restrict__ enc_len,
    float* __restrict__ partials, unsigned int* __restrict__ counter,
    float* __restrict__ out)
{
    const int bid = blockIdx.x;
    const int b   = bid / YMAX;
    const int y   = bid - b * YMAX;
    const int tid = threadIdx.x;            // 0..255, one per token position
    const int lane = tid & 63;
    const int wv   = tid >> 6;

    __shared__ int s_bpos[NW], s_bval[NW], s_epos[NW], s_eval[NW];
    __shared__ int s_wc[8];
    __shared__ int s_cov[T_];               // 16 KiB; coverage ints then tgt0 floats
    __shared__ int s_wsum[4];
    __shared__ float s_part[4];
    __shared__ int s_last;

    // ---- stable compaction of valid begin/end token positions ----
    const int wb = wbeg[b * L_ + tid];
    const int we = wend[b * L_ + tid];
    const bool mb = (wb != -1);
    const bool me = (we != -1);
    unsigned long long balb = __ballot(mb);
    unsigned long long bale = __ballot(me);
    if (lane == 0) { s_wc[wv] = __popcll(balb); s_wc[4 + wv] = __popcll(bale); }
    __syncthreads();

    int offb = 0, offe = 0, nb = 0, ne = 0;
    for (int w = 0; w < 4; ++w) {
        int cb = s_wc[w], ce = s_wc[4 + w];
        if (w < wv) { offb += cb; offe += ce; }
        nb += cb; ne += ce;
    }
    const unsigned long long lmask = (1ull << lane) - 1ull;
    if (mb) {
        int r = offb + __popcll(balb & lmask);
        if (r < NW) { s_bpos[r] = tid; s_bval[r] = sub4i(wb); }
    }
    if (me) {
        int r = offe + __popcll(bale & lmask);
        if (r < NW) { s_epos[r] = tid; s_eval[r] = sub4i(we); }
    }
    __syncthreads();

    const int ylen = nb + 1;

    // ---- this block's row metadata (broadcast LDS reads, wave-uniform) ----
    int lo, hi, tb, te;
    if (y == 0) { lo = 0; hi = 1; tb = 0; te = 0; }
    else {
        int k = y - 1;
        if (k < nb) {
            lo = s_bpos[k] + 1;
            int epos = (k < ne) ? s_epos[k] : L_;
            hi = min(epos + 2, L_);
            tb = s_bval[k];
            te = (k < ne) ? s_eval[k] : -1;
        } else { lo = 0; hi = 0; tb = 0; te = 0; }
    }

    // ---- y==0: build tgt0 = max(0, 1-coverage) in LDS ----
    if (y == 0) {
        const int base = tid * 16;
        #pragma unroll
        for (int j = 0; j < 16; ++j) s_cov[base + j] = 0;
        __syncthreads();
        if (tid < min(nb, NW)) {
            int bv = s_bval[tid];
            int ev = (tid < ne) ? s_eval[tid] : -1;
            int bvc = max(bv, 0);
            int evc = min(ev, T_);
            if (evc > bvc) {
                atomicAdd(&s_cov[bvc], 1);
                if (evc < T_) atomicAdd(&s_cov[evc], -1);
            }
        }
        __syncthreads();
        int run = 0, loc[16];
        #pragma unroll
        for (int j = 0; j < 16; ++j) { run += s_cov[base + j]; loc[j] = run; }
        int x = run;
        for (int d = 1; d < 64; d <<= 1) {
            int t = __shfl_up(x, d, 64);
            if (lane >= d) x += t;
        }
        if (lane == 63) s_wsum[wv] = x;
        __syncthreads();
        int woff = 0;
        for (int w = 0; w < wv; ++w) woff += s_wsum[w];
        const int excl = woff + x - run;
        #pragma unroll
        for (int j = 0; j < 16; ++j)        // overwrite own entries with tgt0
            ((float*)s_cov)[base + j] = fmaxf(0.0f, 1.0f - (float)(excl + loc[j]));
        __syncthreads();
    }

    // ---- BCE over this row's token span ----
    float sum = 0.0f;
    if (y < ylen) {
        const int n_t = enc_len[b];
        const bool two = (hi - lo) > 1;
        const float* __restrict__ p0 = tse + (size_t)b * (L_ * T_) + (size_t)lo * T_;
        const float* __restrict__ p1 = two ? (p0 + T_) : p0;
        const float w1 = two ? 1.0f : 0.0f;
        const float* __restrict__ t0p = (const float*)s_cov;   // y==0 only

        for (int t0 = tid * 4; t0 < n_t; t0 += 1024) {
            const float4 a = *reinterpret_cast<const float4*>(p0 + t0);
            const float4 c = *reinterpret_cast<const float4*>(p1 + t0);
            float xs[4] = {fmaf(w1, c.x, a.x), fmaf(w1, c.y, a.y),
                           fmaf(w1, c.z, a.z), fmaf(w1, c.w, a.w)};
            #pragma unroll
            for (int e = 0; e < 4; ++e) {
                const int t = t0 + e;
                if (t < n_t) {
                    const float xv = xs[e];
                    float tg;
                    if (y == 0) tg = t0p[t];
                    else        tg = (t >= tb && t < te) ? 1.0f : 0.0f;
                    sum += fmaxf(xv, 0.0f) - xv * tg + __logf(1.0f + __expf(-fabsf(xv)));
                }
            }
        }
    }

    // ---- block reduction ----
    for (int d = 32; d > 0; d >>= 1) sum += __shfl_down(sum, d, 64);
    if (lane == 0) s_part[wv] = sum;
    __syncthreads();

    // ---- publish partial; last-arriving block does the final reduction ----
    if (tid == 0) {
        float val = s_part[0] + s_part[1] + s_part[2] + s_part[3];
        __hip_atomic_store(&partials[bid], val, __ATOMIC_RELAXED,
                           __HIP_MEMORY_SCOPE_AGENT);
        unsigned int old = __hip_atomic_fetch_add(counter, 1u, __ATOMIC_ACQ_REL,
                                                  __HIP_MEMORY_SCOPE_AGENT);
        s_last = (old == (unsigned int)(NROW - 1));
    }
    __syncthreads();

    if (s_last) {
        float s = 0.0f;
        for (int i = tid; i < NROW; i += 256)
            s += __hip_atomic_load(&partials[i], __ATOMIC_ACQUIRE,
                                   __HIP_MEMORY_SCOPE_AGENT);
        for (int d = 32; d > 0; d >>= 1) s += __shfl_down(s, d, 64);
        if (lane == 0) s_part[wv] = s;
        __syncthreads();
        if (tid == 0) {
            const float tot = s_part[0] + s_part[1] + s_part[2] + s_part[3];
            const float inv_total =
                (float)(1.0 / ((double)B_ * (double)YMAX * (double)T_));
            out[0] = tot * inv_total;
        }
    }
}

extern "C" void kernel_launch(void* const* d_in, const int* in_sizes, int n_in,
                              void* d_out, int out_size, void* d_ws, size_t ws_size,
                              hipStream_t stream)
{
    const float* tse  = (const float*)d_in[0];   // [B, L, T] f32
    const int*   wbeg = (const int*)  d_in[1];   // [B, L] i32
    const int*   wend = (const int*)  d_in[2];   // [B, L] i32
    const int*   enc  = (const int*)  d_in[3];   // [B] i32
    // d_in[4] = y_max (129) — hard-coded as YMAX

    float*        partials = (float*)d_ws;           // NROW floats
    unsigned int* counter  = (unsigned int*)(partials + NROW);
    float*        outp     = (float*)d_out;

    // counter must start at 0 (ws is 0xAA-poisoned); memset is capturable
    hipMemsetAsync(counter, 0, sizeof(unsigned int), stream);
    fused_kernel<<<NROW, 256, 0, stream>>>(tse, wbeg, wend, enc,
                                           partials, counter, outp);
}

// Round 4
// 186.970 us; speedup vs baseline: 1.5919x; 1.5919x over previous
//
#include <hip/hip_runtime.h>

#define B_   32
#define L_   256
#define T_   4096
#define YMAX 129            // y_max = W+1
#define NW   128            // n_words
#define NROW (B_ * YMAX)    // 4128

// sub4(v) = ((v-1)//2 - 1)//2 with Python floor semantics
__device__ __forceinline__ int sub4i(int v) {
    return (((v - 1) >> 1) - 1) >> 1;
}

// ---------------------------------------------------------------------------
// Fused main kernel. One block per (b, y):
//  1. recompute row metadata from wbeg/wend (ballot/popcount compaction; the
//     2 KB index rows are shared by all 129 blocks of a batch -> L2 hits)
//  2. y==0 blocks build tgt0 in LDS via diff-array + block scan
//  3. BCE over the row's <=2 token rows (float4, each tse element read once)
//  4. plain store of the block partial; a separate 1-block kernel reduces.
//     (NO ordered agent-scope atomics: R3 showed acq_rel/acquire lowering
//      emits per-op L2 writeback/invalidate -> 150 us of cache-maintenance.)
// ---------------------------------------------------------------------------
__global__ __launch_bounds__(256) void fused_kernel(
    const float* __restrict__ tse, const int* __restrict__ wbeg,
    const int* __restrict__ wend, const int* __restrict__ enc_len,
    float* __restrict__ partials)
{
    const int bid = blockIdx.x;
    const int b   = bid / YMAX;
    const int y   = bid - b * YMAX;
    const int tid = threadIdx.x;            // 0..255, one per token position
    const int lane = tid & 63;
    const int wv   = tid >> 6;

    __shared__ int s_bpos[NW], s_bval[NW], s_epos[NW], s_eval[NW];
    __shared__ int s_wc[8];
    __shared__ int s_cov[T_];               // 16 KiB; coverage ints then tgt0 floats
    __shared__ int s_wsum[4];
    __shared__ float s_part[4];

    // ---- stable compaction of valid begin/end token positions ----
    const int wb = wbeg[b * L_ + tid];
    const int we = wend[b * L_ + tid];
    const bool mb = (wb != -1);
    const bool me = (we != -1);
    unsigned long long balb = __ballot(mb);
    unsigned long long bale = __ballot(me);
    if (lane == 0) { s_wc[wv] = __popcll(balb); s_wc[4 + wv] = __popcll(bale); }
    __syncthreads();

    int offb = 0, offe = 0, nb = 0, ne = 0;
    for (int w = 0; w < 4; ++w) {
        int cb = s_wc[w], ce = s_wc[4 + w];
        if (w < wv) { offb += cb; offe += ce; }
        nb += cb; ne += ce;
    }
    const unsigned long long lmask = (1ull << lane) - 1ull;
    if (mb) {
        int r = offb + __popcll(balb & lmask);
        if (r < NW) { s_bpos[r] = tid; s_bval[r] = sub4i(wb); }
    }
    if (me) {
        int r = offe + __popcll(bale & lmask);
        if (r < NW) { s_epos[r] = tid; s_eval[r] = sub4i(we); }
    }
    __syncthreads();

    const int ylen = nb + 1;

    // ---- this block's row metadata (broadcast LDS reads, wave-uniform) ----
    int lo, hi, tb, te;
    if (y == 0) { lo = 0; hi = 1; tb = 0; te = 0; }
    else {
        int k = y - 1;
        if (k < nb) {
            lo = s_bpos[k] + 1;
            int epos = (k < ne) ? s_epos[k] : L_;
            hi = min(epos + 2, L_);
            tb = s_bval[k];
            te = (k < ne) ? s_eval[k] : -1;
        } else { lo = 0; hi = 0; tb = 0; te = 0; }
    }

    // ---- y==0: build tgt0 = max(0, 1-coverage) in LDS ----
    if (y == 0) {
        const int base = tid * 16;
        #pragma unroll
        for (int j = 0; j < 16; ++j) s_cov[base + j] = 0;
        __syncthreads();
        if (tid < min(nb, NW)) {
            int bv = s_bval[tid];
            int ev = (tid < ne) ? s_eval[tid] : -1;
            int bvc = max(bv, 0);
            int evc = min(ev, T_);
            if (evc > bvc) {
                atomicAdd(&s_cov[bvc], 1);
                if (evc < T_) atomicAdd(&s_cov[evc], -1);
            }
        }
        __syncthreads();
        int run = 0, loc[16];
        #pragma unroll
        for (int j = 0; j < 16; ++j) { run += s_cov[base + j]; loc[j] = run; }
        int x = run;
        for (int d = 1; d < 64; d <<= 1) {
            int t = __shfl_up(x, d, 64);
            if (lane >= d) x += t;
        }
        if (lane == 63) s_wsum[wv] = x;
        __syncthreads();
        int woff = 0;
        for (int w = 0; w < wv; ++w) woff += s_wsum[w];
        const int excl = woff + x - run;
        #pragma unroll
        for (int j = 0; j < 16; ++j)        // overwrite own entries with tgt0
            ((float*)s_cov)[base + j] = fmaxf(0.0f, 1.0f - (float)(excl + loc[j]));
        __syncthreads();
    }

    // ---- BCE over this row's token span ----
    float sum = 0.0f;
    if (y < ylen) {
        const int n_t = enc_len[b];
        const bool two = (hi - lo) > 1;
        const float* __restrict__ p0 = tse + (size_t)b * (L_ * T_) + (size_t)lo * T_;
        const float* __restrict__ p1 = two ? (p0 + T_) : p0;
        const float w1 = two ? 1.0f : 0.0f;
        const float* __restrict__ t0p = (const float*)s_cov;   // y==0 only

        for (int t0 = tid * 4; t0 < n_t; t0 += 1024) {
            const float4 a = *reinterpret_cast<const float4*>(p0 + t0);
            const float4 c = *reinterpret_cast<const float4*>(p1 + t0);
            float xs[4] = {fmaf(w1, c.x, a.x), fmaf(w1, c.y, a.y),
                           fmaf(w1, c.z, a.z), fmaf(w1, c.w, a.w)};
            #pragma unroll
            for (int e = 0; e < 4; ++e) {
                const int t = t0 + e;
                if (t < n_t) {
                    const float xv = xs[e];
                    float tg;
                    if (y == 0) tg = t0p[t];
                    else        tg = (t >= tb && t < te) ? 1.0f : 0.0f;
                    sum += fmaxf(xv, 0.0f) - xv * tg + __logf(1.0f + __expf(-fabsf(xv)));
                }
            }
        }
    }

    // ---- block reduction, plain store of partial ----
    for (int d = 32; d > 0; d >>= 1) sum += __shfl_down(sum, d, 64);
    if (lane == 0) s_part[wv] = sum;
    __syncthreads();
    if (tid == 0)
        partials[bid] = s_part[0] + s_part[1] + s_part[2] + s_part[3];
}

// ---------------------------------------------------------------------------
// Single-block final reduction (kernel boundary = visibility guarantee).
// ---------------------------------------------------------------------------
__global__ __launch_bounds__(256) void reduce_kernel(
    const float* __restrict__ partials, float* __restrict__ out)
{
    const int tid = threadIdx.x;
    float sum = 0.0f;
    for (int i = tid; i < NROW; i += 256) sum += partials[i];
    const int lane = tid & 63;
    const int wv   = tid >> 6;
    for (int d = 32; d > 0; d >>= 1) sum += __shfl_down(sum, d, 64);
    __shared__ float s_part[4];
    if (lane == 0) s_part[wv] = sum;
    __syncthreads();
    if (tid == 0) {
        const float tot = s_part[0] + s_part[1] + s_part[2] + s_part[3];
        const float inv_total = (float)(1.0 / ((double)B_ * (double)YMAX * (double)T_));
        out[0] = tot * inv_total;
    }
}

extern "C" void kernel_launch(void* const* d_in, const int* in_sizes, int n_in,
                              void* d_out, int out_size, void* d_ws, size_t ws_size,
                              hipStream_t stream)
{
    const float* tse  = (const float*)d_in[0];   // [B, L, T] f32
    const int*   wbeg = (const int*)  d_in[1];   // [B, L] i32
    const int*   wend = (const int*)  d_in[2];   // [B, L] i32
    const int*   enc  = (const int*)  d_in[3];   // [B] i32
    // d_in[4] = y_max (129) — hard-coded as YMAX

    float* partials = (float*)d_ws;              // NROW floats
    float* outp     = (float*)d_out;

    fused_kernel<<<NROW, 256, 0, stream>>>(tse, wbeg, wend, enc, partials);
    reduce_kernel<<<1, 256, 0, stream>>>(partials, outp);
}

// Round 5
// 186.474 us; speedup vs baseline: 1.5961x; 1.0027x over previous
//
#include <hip/hip_runtime.h>

#define B_   32
#define L_   256
#define T_   4096
#define YMAX 129            // y_max = W+1
#define NW   128            // n_words
#define NROW (B_ * YMAX)    // 4128

// sub4(v) = ((v-1)//2 - 1)//2 with Python floor semantics
__device__ __forceinline__ int sub4i(int v) {
    return (((v - 1) >> 1) - 1) >> 1;
}

// ---------------------------------------------------------------------------
// Fused main kernel. One block per (b, y):
//  1. recompute row metadata from wbeg/wend (ballot/popcount compaction; the
//     2 KB index rows are shared by all 129 blocks of a batch -> L2 hits)
//  2. y==0 blocks build tgt0 in LDS via diff-array + block scan
//  3. BCE over the row's <=2 token rows; 8 frames/thread/iter (4 float4 in
//     flight) -> 1.6 iterations, latency-hiding via MLP (data is L3-resident)
//  4. plain store of the block partial; separate 1-block kernel reduces.
//     (NO ordered agent-scope atomics: R3 showed acq_rel/acquire lowering
//      emits per-op L2 writeback/invalidate -> 150 us of cache-maintenance.)
// ---------------------------------------------------------------------------
__global__ __launch_bounds__(256) void fused_kernel(
    const float* __restrict__ tse, const int* __restrict__ wbeg,
    const int* __restrict__ wend, const int* __restrict__ enc_len,
    float* __restrict__ partials)
{
    const int bid = blockIdx.x;
    const int b   = bid / YMAX;
    const int y   = bid - b * YMAX;
    const int tid = threadIdx.x;            // 0..255, one per token position
    const int lane = tid & 63;
    const int wv   = tid >> 6;

    __shared__ int s_bpos[NW], s_bval[NW], s_epos[NW], s_eval[NW];
    __shared__ int s_wc[8];
    __shared__ int s_cov[T_];               // 16 KiB; coverage ints then tgt0 floats
    __shared__ int s_wsum[4];
    __shared__ float s_part[4];

    const int n_t = enc_len[b];             // hoisted: overlaps prologue latency

    // ---- stable compaction of valid begin/end token positions ----
    const int wb = wbeg[b * L_ + tid];
    const int we = wend[b * L_ + tid];
    const bool mb = (wb != -1);
    const bool me = (we != -1);
    unsigned long long balb = __ballot(mb);
    unsigned long long bale = __ballot(me);
    if (lane == 0) { s_wc[wv] = __popcll(balb); s_wc[4 + wv] = __popcll(bale); }
    __syncthreads();

    int offb = 0, offe = 0, nb = 0, ne = 0;
    for (int w = 0; w < 4; ++w) {
        int cb = s_wc[w], ce = s_wc[4 + w];
        if (w < wv) { offb += cb; offe += ce; }
        nb += cb; ne += ce;
    }
    const unsigned long long lmask = (1ull << lane) - 1ull;
    if (mb) {
        int r = offb + __popcll(balb & lmask);
        if (r < NW) { s_bpos[r] = tid; s_bval[r] = sub4i(wb); }
    }
    if (me) {
        int r = offe + __popcll(bale & lmask);
        if (r < NW) { s_epos[r] = tid; s_eval[r] = sub4i(we); }
    }
    __syncthreads();

    const int ylen = nb + 1;

    // ---- this block's row metadata (broadcast LDS reads, wave-uniform) ----
    int lo, hi, tb, te;
    if (y == 0) { lo = 0; hi = 1; tb = 0; te = 0; }
    else {
        int k = y - 1;
        if (k < nb) {
            lo = s_bpos[k] + 1;
            int epos = (k < ne) ? s_epos[k] : L_;
            hi = min(epos + 2, L_);
            tb = s_bval[k];
            te = (k < ne) ? s_eval[k] : -1;
        } else { lo = 0; hi = 0; tb = 0; te = 0; }
    }

    // ---- y==0: build tgt0 = max(0, 1-coverage) in LDS ----
    if (y == 0) {
        const int base = tid * 16;
        #pragma unroll
        for (int j = 0; j < 16; ++j) s_cov[base + j] = 0;
        __syncthreads();
        if (tid < min(nb, NW)) {
            int bv = s_bval[tid];
            int ev = (tid < ne) ? s_eval[tid] : -1;
            int bvc = max(bv, 0);
            int evc = min(ev, T_);
            if (evc > bvc) {
                atomicAdd(&s_cov[bvc], 1);
                if (evc < T_) atomicAdd(&s_cov[evc], -1);
            }
        }
        __syncthreads();
        int run = 0, loc[16];
        #pragma unroll
        for (int j = 0; j < 16; ++j) { run += s_cov[base + j]; loc[j] = run; }
        int x = run;
        for (int d = 1; d < 64; d <<= 1) {
            int t = __shfl_up(x, d, 64);
            if (lane >= d) x += t;
        }
        if (lane == 63) s_wsum[wv] = x;
        __syncthreads();
        int woff = 0;
        for (int w = 0; w < wv; ++w) woff += s_wsum[w];
        const int excl = woff + x - run;
        #pragma unroll
        for (int j = 0; j < 16; ++j)        // overwrite own entries with tgt0
            ((float*)s_cov)[base + j] = fmaxf(0.0f, 1.0f - (float)(excl + loc[j]));
        __syncthreads();
    }

    // ---- BCE over this row's token span: 8 frames/thread/iter ----
    float sum = 0.0f;
    if (y < ylen) {
        const bool two = (hi - lo) > 1;
        const float* __restrict__ p0 = tse + (size_t)b * (L_ * T_) + (size_t)lo * T_;
        const float* __restrict__ p1 = two ? (p0 + T_) : p0;
        const float w1 = two ? 1.0f : 0.0f;
        const float* __restrict__ t0p = (const float*)s_cov;   // y==0 only

        for (int t0 = tid * 8; t0 < n_t; t0 += 2048) {
            // t0 multiple of 8, t0 < n_t <= 4096 => t0+7 <= 4095: loads safe
            const float4 a0 = *reinterpret_cast<const float4*>(p0 + t0);
            const float4 a1 = *reinterpret_cast<const float4*>(p0 + t0 + 4);
            const float4 c0 = *reinterpret_cast<const float4*>(p1 + t0);
            const float4 c1 = *reinterpret_cast<const float4*>(p1 + t0 + 4);
            float xs[8] = {fmaf(w1, c0.x, a0.x), fmaf(w1, c0.y, a0.y),
                           fmaf(w1, c0.z, a0.z), fmaf(w1, c0.w, a0.w),
                           fmaf(w1, c1.x, a1.x), fmaf(w1, c1.y, a1.y),
                           fmaf(w1, c1.z, a1.z), fmaf(w1, c1.w, a1.w)};
            #pragma unroll
            for (int e = 0; e < 8; ++e) {
                const int t = t0 + e;
                const float xv = xs[e];
                float tg;
                if (y == 0) tg = t0p[t];
                else        tg = (t >= tb && t < te) ? 1.0f : 0.0f;
                const float bce = fmaxf(xv, 0.0f) - xv * tg
                                + __logf(1.0f + __expf(-fabsf(xv)));
                sum += (t < n_t) ? bce : 0.0f;   // branchless tail mask
            }
        }
    }

    // ---- block reduction, plain store of partial ----
    for (int d = 32; d > 0; d >>= 1) sum += __shfl_down(sum, d, 64);
    if (lane == 0) s_part[wv] = sum;
    __syncthreads();
    if (tid == 0)
        partials[bid] = s_part[0] + s_part[1] + s_part[2] + s_part[3];
}

// ---------------------------------------------------------------------------
// Single-block final reduction (kernel boundary = visibility guarantee).
// ---------------------------------------------------------------------------
__global__ __launch_bounds__(256) void reduce_kernel(
    const float* __restrict__ partials, float* __restrict__ out)
{
    const int tid = threadIdx.x;
    float sum = 0.0f;
    for (int i = tid; i < NROW; i += 256) sum += partials[i];
    const int lane = tid & 63;
    const int wv   = tid >> 6;
    for (int d = 32; d > 0; d >>= 1) sum += __shfl_down(sum, d, 64);
    __shared__ float s_part[4];
    if (lane == 0) s_part[wv] = sum;
    __syncthreads();
    if (tid == 0) {
        const float tot = s_part[0] + s_part[1] + s_part[2] + s_part[3];
        const float inv_total = (float)(1.0 / ((double)B_ * (double)YMAX * (double)T_));
        out[0] = tot * inv_total;
    }
}

extern "C" void kernel_launch(void* const* d_in, const int* in_sizes, int n_in,
                              void* d_out, int out_size, void* d_ws, size_t ws_size,
                              hipStream_t stream)
{
    const float* tse  = (const float*)d_in[0];   // [B, L, T] f32
    const int*   wbeg = (const int*)  d_in[1];   // [B, L] i32
    const int*   wend = (const int*)  d_in[2];   // [B, L] i32
    const int*   enc  = (const int*)  d_in[3];   // [B] i32
    // d_in[4] = y_max (129) — hard-coded as YMAX

    float* partials = (float*)d_ws;              // NROW floats
    float* outp     = (float*)d_out;

    fused_kernel<<<NROW, 256, 0, stream>>>(tse, wbeg, wend, enc, partials);
    reduce_kernel<<<1, 256, 0, stream>>>(partials, outp);
}